// Round 7
// baseline (349.258 us; speedup 1.0000x reference)
//
#include <hip/hip_runtime.h>
#include <math.h>

// Round 7: dispatch packing. Same math/numerics as R6; GEMM core refactored to
// a __device__ body on dynamic LDS so independent stages share dispatches:
//   D1 prep_w    : split Wq, Wk (natural) + transpose-split Wv
//   D2 xsplit_mt : split X (hi/lo bf16 + f16)  ||  Mt = Wk Wq^T (split 3-MFMA)
//   D3 t_and_v   : T = Xs.Mt_s (split)  ||  Vt = (X.Wv)^T (fused transpose)
//   D4 scores    : Sc = T . Xf^T (f16, BK=64 swizzled)
//   D5 softmax   : P = softmax(Sc) -> f16
//   D6 pv        : out = P . Vt^T

typedef __bf16 bf16;
typedef _Float16 f16;
typedef __bf16 bf16x8 __attribute__((ext_vector_type(8)));
typedef __bf16 bf16x4 __attribute__((ext_vector_type(4)));
typedef _Float16 f16x4 __attribute__((ext_vector_type(4)));
typedef _Float16 f16x8 __attribute__((ext_vector_type(8)));
typedef float  f32x4  __attribute__((ext_vector_type(4)));

template<typename E> struct vec8_of;
template<> struct vec8_of<bf16> { using type = bf16x8; };
template<> struct vec8_of<f16>  { using type = f16x8; };

__device__ inline f32x4 mfma16(bf16x8 a, bf16x8 b, f32x4 c) {
    return __builtin_amdgcn_mfma_f32_16x16x32_bf16(a, b, c, 0, 0, 0);
}
__device__ inline f32x4 mfma16(f16x8 a, f16x8 b, f32x4 c) {
    return __builtin_amdgcn_mfma_f32_16x16x32_f16(a, b, c, 0, 0, 0);
}

#define AS1 __attribute__((address_space(1)))
#define AS3 __attribute__((address_space(3)))

template<typename E>
__device__ inline void async_load16(const E* g, void* l) {
    __builtin_amdgcn_global_load_lds((const AS1 unsigned int*)g,
                                     (AS3 unsigned int*)l, 16, 0, 0);
}

// C[M,N] = sum_k A[m,k]*B[n,k]  (B passed [N,K]-layout, leading dim ldb).
// SPLIT: hi/lo pairs, hh + hl + lh. BK: K-tile (32 split, 64 plain).
// OUT_MODE: 0 fp32; 1 f16; 2 f16 transposed per-batch (V path); 3 bf16 hi/lo.
template<typename E, bool SPLIT, int OUT_MODE, int BK>
__device__ __forceinline__ void gemm_body(
    char* __restrict__ smraw,
    const E* __restrict__ Ahi, const E* __restrict__ Alo,
    const E* __restrict__ Bhi, const E* __restrict__ Blo,
    float* __restrict__ Cf, f16* __restrict__ Ch,
    bf16* __restrict__ Cbh, bf16* __restrict__ Cbl,
    int K, int lda, int ldb, int ldc,
    long long sA, long long sB, long long sC,
    int bx, int by, int bz)
{
    using vec8 = typename vec8_of<E>::type;
    constexpr int TILE_BYTES = 128 * BK * (int)sizeof(E);   // 8192 or 16384
    constexpr int CPW = (TILE_BYTES / 1024) / 4;            // 1KB chunks per wave
    constexpr int SPR = (BK * (int)sizeof(E)) / 16;         // 16B slots per row
    constexpr int SWZ = (SPR == 8) ? 7 : 0;                 // swizzle mask (BK=64)

    Ahi += (long long)bz * sA;
    Bhi += (long long)bz * sB;
    if (SPLIT) { Alo += (long long)bz * sA; Blo += (long long)bz * sB; }

    const int tid  = threadIdx.x;
    const int lane = tid & 63;
    const int wave = tid >> 6;
    const int quad = lane >> 4;
    const int l16  = lane & 15;
    const int wm   = (wave >> 1) * 64;
    const int wn   = (wave & 1) * 64;

    const long long rowA0 = (long long)by * 128;
    const long long colB0 = (long long)bx * 128;

    int ofs[CPW], rr[CPW], cc8[CPW];
#pragma unroll
    for (int u = 0; u < CPW; u++) {
        ofs[u] = (wave * CPW + u) * 1024 + lane * 16;
        const int s = ofs[u] >> 4;
        rr[u]  = s / SPR;
        cc8[u] = (s & (SPR - 1)) ^ (rr[u] & SWZ);
    }

    f32x4 acc[4][4];
#pragma unroll
    for (int i = 0; i < 4; i++)
#pragma unroll
        for (int j = 0; j < 4; j++) acc[i][j] = (f32x4){0.f, 0.f, 0.f, 0.f};

    for (int k0 = 0; k0 < K; k0 += BK) {
#pragma unroll
        for (int u = 0; u < CPW; u++) {
            async_load16(Ahi + (rowA0 + rr[u]) * lda + k0 + cc8[u] * 8, smraw + 0 * TILE_BYTES + ofs[u]);
            async_load16(Bhi + (colB0 + rr[u]) * ldb + k0 + cc8[u] * 8, smraw + 1 * TILE_BYTES + ofs[u]);
            if (SPLIT) {
                async_load16(Alo + (rowA0 + rr[u]) * lda + k0 + cc8[u] * 8, smraw + 2 * TILE_BYTES + ofs[u]);
                async_load16(Blo + (colB0 + rr[u]) * ldb + k0 + cc8[u] * 8, smraw + 3 * TILE_BYTES + ofs[u]);
            }
        }
        __syncthreads();

#pragma unroll
        for (int kh = 0; kh < BK / 32; kh++) {
            const int kc8 = kh * 4 + quad;    // 16B chunk index within row
            vec8 a_hi[4], b_hi[4], a_lo[4], b_lo[4];
#pragma unroll
            for (int i = 0; i < 4; i++) {
                const int ra = wm + i * 16 + l16;
                const int rb = wn + i * 16 + l16;
                const int oa = ra * (SPR * 16) + ((kc8 ^ (ra & SWZ)) << 4);
                const int ob = rb * (SPR * 16) + ((kc8 ^ (rb & SWZ)) << 4);
                a_hi[i] = *(const vec8*)(smraw + 0 * TILE_BYTES + oa);
                b_hi[i] = *(const vec8*)(smraw + 1 * TILE_BYTES + ob);
                if (SPLIT) {
                    a_lo[i] = *(const vec8*)(smraw + 2 * TILE_BYTES + oa);
                    b_lo[i] = *(const vec8*)(smraw + 3 * TILE_BYTES + ob);
                }
            }
#pragma unroll
            for (int i = 0; i < 4; i++)
#pragma unroll
                for (int j = 0; j < 4; j++) {
                    acc[i][j] = mfma16(a_hi[i], b_hi[j], acc[i][j]);
                    if (SPLIT) {
                        acc[i][j] = mfma16(a_hi[i], b_lo[j], acc[i][j]);
                        acc[i][j] = mfma16(a_lo[i], b_hi[j], acc[i][j]);
                    }
                }
        }
        __syncthreads();
    }

    if (OUT_MODE == 2) {
        auto tr = (f16(*)[130])smraw;    // 128 x 130 f16 = 33280 B
#pragma unroll
        for (int i = 0; i < 4; i++)
#pragma unroll
            for (int j = 0; j < 4; j++)
#pragma unroll
                for (int e = 0; e < 4; e++)
                    tr[wn + j * 16 + l16][wm + i * 16 + quad * 4 + e] = (f16)acc[i][j][e];
        __syncthreads();
        const int batch = (int)(rowA0 >> 11);
        const int rib   = (int)(rowA0 & 2047);
        const int c  = tid >> 1;
        const int r0 = (tid & 1) << 6;
        f16* vt = Ch + (long long)batch * 1024 * 2048 + (long long)(colB0 + c) * ldc + rib + r0;
#pragma unroll
        for (int u = 0; u < 64; u += 8)
            *(f16x8*)(vt + u) = *(const f16x8*)&tr[c][r0 + u];
        return;
    }

    const long long cOff = (long long)bz * sC +
                           (rowA0 + wm + quad * 4) * (long long)ldc + colB0 + wn + l16;
#pragma unroll
    for (int i = 0; i < 4; i++)
#pragma unroll
        for (int e = 0; e < 4; e++) {
            const long long ro = cOff + (i * 16 + e) * ldc;
            if (OUT_MODE == 0) {
                float* rp = Cf + ro;
#pragma unroll
                for (int j = 0; j < 4; j++) rp[j * 16] = acc[i][j][e];
            } else if (OUT_MODE == 1) {
                f16* rp = Ch + ro;
#pragma unroll
                for (int j = 0; j < 4; j++) rp[j * 16] = (f16)acc[i][j][e];
            } else {  // OUT_MODE 3
                bf16* rh = Cbh + ro;
                bf16* rl = Cbl + ro;
#pragma unroll
                for (int j = 0; j < 4; j++) {
                    float v = acc[i][j][e];
                    bf16 h = (bf16)v;
                    rh[j * 16] = h;
                    rl[j * 16] = (bf16)(v - (float)h);
                }
            }
        }
}

// ---- D1: weight prep. blocks 0..1023 Wq-split, 1024..2047 Wk-split,
//          2048..3071 Wv transpose-split (32x32 tiles).
__global__ __launch_bounds__(256) void prep_w(
    const float* __restrict__ Wq, const float* __restrict__ Wk, const float* __restrict__ Wv,
    bf16* __restrict__ Wq_h, bf16* __restrict__ Wq_l,
    bf16* __restrict__ Wk_h, bf16* __restrict__ Wk_l,
    bf16* __restrict__ Wvt_h, bf16* __restrict__ Wvt_l)
{
    int b = blockIdx.x;
    if (b < 2048) {
        const float4* W = (const float4*)(b < 1024 ? Wq : Wk);
        bf16* hh = b < 1024 ? Wq_h : Wk_h;
        bf16* ll = b < 1024 ? Wq_l : Wk_l;
        long long i = (long long)(b & 1023) * 256 + threadIdx.x;
        float4 v = W[i];
        bf16 a0 = (bf16)v.x, a1 = (bf16)v.y, a2 = (bf16)v.z, a3 = (bf16)v.w;
        bf16x4 hv = {a0, a1, a2, a3};
        bf16x4 lv = {(bf16)(v.x - (float)a0), (bf16)(v.y - (float)a1),
                     (bf16)(v.z - (float)a2), (bf16)(v.w - (float)a3)};
        *(bf16x4*)(hh + 4 * i) = hv;
        *(bf16x4*)(ll + 4 * i) = lv;
    } else {
        b -= 2048;
        __shared__ float t[32][33];
        const int bx = (b & 31) * 32, by = (b >> 5) * 32;
        const int tx = threadIdx.x & 31, ty = threadIdx.x >> 5;
#pragma unroll
        for (int i = 0; i < 32; i += 8)
            t[ty + i][tx] = Wv[(long long)(by + ty + i) * 1024 + bx + tx];
        __syncthreads();
#pragma unroll
        for (int i = 0; i < 32; i += 8) {
            float v = t[tx][ty + i];
            long long o = (long long)(bx + ty + i) * 1024 + by + tx;
            bf16 h = (bf16)v;
            Wvt_h[o] = h;
            Wvt_l[o] = (bf16)(v - (float)h);
        }
    }
}

// ---- D2: split X (blocks 0..8191)  ||  Mt = Wk Wq^T (blocks 8192..8255)
__global__ __launch_bounds__(256) void xsplit_mt(
    const float4* __restrict__ X,
    bf16* __restrict__ Xhi, bf16* __restrict__ Xlo, f16* __restrict__ Xf,
    const bf16* __restrict__ Wk_h, const bf16* __restrict__ Wk_l,
    const bf16* __restrict__ Wq_h, const bf16* __restrict__ Wq_l,
    bf16* __restrict__ Mt_h, bf16* __restrict__ Mt_l)
{
    extern __shared__ char smraw[];
    int b = blockIdx.x;
    if (b < 8192) {
        long long i = (long long)b * 256 + threadIdx.x;
        float4 v = X[i];
        bf16 h0 = (bf16)v.x, h1 = (bf16)v.y, h2 = (bf16)v.z, h3 = (bf16)v.w;
        bf16x4 hv = {h0, h1, h2, h3};
        bf16x4 lv = {(bf16)(v.x - (float)h0), (bf16)(v.y - (float)h1),
                     (bf16)(v.z - (float)h2), (bf16)(v.w - (float)h3)};
        *(bf16x4*)(Xhi + 4 * i) = hv;
        *(bf16x4*)(Xlo + 4 * i) = lv;
        f16x4 fv = {(f16)v.x, (f16)v.y, (f16)v.z, (f16)v.w};
        *(f16x4*)(Xf + 4 * i) = fv;
    } else {
        b -= 8192;
        gemm_body<bf16, true, 3, 32>(smraw, Wk_h, Wk_l, Wq_h, Wq_l,
                                     nullptr, nullptr, Mt_h, Mt_l,
                                     1024, 1024, 1024, 1024, 0, 0, 0,
                                     b & 7, b >> 3, 0);
    }
}

// ---- D3: T = Xsplit.Mt_split (z=0)  ||  Vt = (X.Wv)^T (z=1)
__global__ __launch_bounds__(256) void t_and_v(
    const bf16* __restrict__ Xhi, const bf16* __restrict__ Xlo,
    const bf16* __restrict__ Mt_h, const bf16* __restrict__ Mt_l,
    const bf16* __restrict__ Wvt_h,
    f16* __restrict__ T, f16* __restrict__ Vt)
{
    extern __shared__ char smraw[];
    if (blockIdx.z == 0)
        gemm_body<bf16, true, 1, 32>(smraw, Xhi, Xlo, Mt_h, Mt_l,
                                     nullptr, T, nullptr, nullptr,
                                     1024, 1024, 1024, 1024, 0, 0, 0,
                                     blockIdx.x, blockIdx.y, 0);
    else
        gemm_body<bf16, false, 2, 64>(smraw, Xhi, nullptr, Wvt_h, nullptr,
                                      nullptr, Vt, nullptr, nullptr,
                                      1024, 1024, 1024, 2048, 0, 0, 0,
                                      blockIdx.x, blockIdx.y, 0);
}

// ---- D4/D6: plain GEMM wrapper
template<typename E, bool SPLIT, int OUT_MODE, int BK>
__global__ __launch_bounds__(256) void gemm_bt(
    const E* __restrict__ Ahi, const E* __restrict__ Alo,
    const E* __restrict__ Bhi, const E* __restrict__ Blo,
    float* __restrict__ Cf, f16* __restrict__ Ch,
    bf16* __restrict__ Cbh, bf16* __restrict__ Cbl,
    int K, int lda, int ldb, int ldc,
    long long sA, long long sB, long long sC)
{
    extern __shared__ char smraw[];
    gemm_body<E, SPLIT, OUT_MODE, BK>(smraw, Ahi, Alo, Bhi, Blo, Cf, Ch, Cbh, Cbl,
                                      K, lda, ldb, ldc, sA, sB, sC,
                                      blockIdx.x, blockIdx.y, blockIdx.z);
}

// ---- D5: row softmax fp32 -> f16.
__global__ __launch_bounds__(256) void softmax_f16(const float* __restrict__ S,
                                                   f16* __restrict__ P, int n)
{
    const long long row = blockIdx.x;
    const float* p = S + row * (long long)n;
    f16* q = P + row * (long long)n;
    const int tid = threadIdx.x;
    const int wv = tid >> 6, lane = tid & 63;

    float v[8];
    float m = -3.4e38f;
#pragma unroll
    for (int i = 0; i < 8; i++) { v[i] = p[tid + (i << 8)]; m = fmaxf(m, v[i]); }
#pragma unroll
    for (int off = 32; off > 0; off >>= 1) m = fmaxf(m, __shfl_xor(m, off, 64));

    __shared__ float red[4];
    if (lane == 0) red[wv] = m;
    __syncthreads();
    m = fmaxf(fmaxf(red[0], red[1]), fmaxf(red[2], red[3]));

    float s = 0.f;
#pragma unroll
    for (int i = 0; i < 8; i++) { v[i] = __expf(v[i] - m); s += v[i]; }
#pragma unroll
    for (int off = 32; off > 0; off >>= 1) s += __shfl_xor(s, off, 64);
    __syncthreads();
    if (lane == 0) red[wv] = s;
    __syncthreads();
    s = red[0] + red[1] + red[2] + red[3];

    const float inv = 1.0f / s;
#pragma unroll
    for (int i = 0; i < 8; i++) q[tid + (i << 8)] = (f16)(v[i] * inv);
}

extern "C" void kernel_launch(void* const* d_in, const int* in_sizes, int n_in,
                              void* d_out, int out_size, void* d_ws, size_t ws_size,
                              hipStream_t stream) {
    const float* X  = (const float*)d_in[0];   // [8192,1024]
    const float* Wq = (const float*)d_in[1];   // [1024,1024]
    const float* Wk = (const float*)d_in[2];
    const float* Wv = (const float*)d_in[3];
    float* out = (float*)d_out;                // [8192,1024]

    char* w = (char*)d_ws;
    const long long MB = 1024LL * 1024;
    bf16* Xhi   = (bf16*)(w + 0 * MB);     // 16 MB
    bf16* Xlo   = (bf16*)(w + 16 * MB);    // 16 MB
    f16*  Xf    = (f16*) (w + 32 * MB);    // 16 MB
    bf16* Wq_h  = (bf16*)(w + 48 * MB);    // 2 MB (natural layout)
    bf16* Wq_l  = (bf16*)(w + 50 * MB);
    bf16* Wk_h  = (bf16*)(w + 52 * MB);
    bf16* Wk_l  = (bf16*)(w + 54 * MB);
    bf16* Wvt_h = (bf16*)(w + 56 * MB);    // 2 MB (transposed)
    bf16* Wvt_l = (bf16*)(w + 58 * MB);
    bf16* Mt_h  = (bf16*)(w + 60 * MB);    // 2 MB
    bf16* Mt_l  = (bf16*)(w + 62 * MB);    // 2 MB
    f16*  T     = (f16*) (w + 64 * MB);    // 16 MB [8192,1024]
    f16*  Vt    = (f16*) (w + 80 * MB);    // 16 MB [4][1024][2048]
    float* Sc   = (float*)(w + 96 * MB);   // 64 MB
    f16*  P     = (f16*) (w + 160 * MB);   // 32 MB -> ends 192 MB

    dim3 blk(256);

    // D1: weight prep (Wq-split | Wk-split | Wv transpose-split)
    prep_w<<<dim3(3072), blk, 0, stream>>>(Wq, Wk, Wv,
                                           Wq_h, Wq_l, Wk_h, Wk_l, Wvt_h, Wvt_l);

    // D2: split X || Mt = Wk Wq^T
    xsplit_mt<<<dim3(8192 + 64), blk, 32768, stream>>>(
        (const float4*)X, Xhi, Xlo, Xf, Wk_h, Wk_l, Wq_h, Wq_l, Mt_h, Mt_l);

    // D3: T || Vt   (grid z: 0 = T, 1 = V; 33280 B dynamic LDS for V transpose)
    t_and_v<<<dim3(8, 64, 2), blk, 33280, stream>>>(
        Xhi, Xlo, Mt_h, Mt_l, Wvt_h, T, Vt);

    // D4: Sc = T . Xf^T per batch (f16, BK=64 swizzled), fp32 out
    gemm_bt<f16, false, 0, 64><<<dim3(16, 16, 4), blk, 32768, stream>>>(
        T, nullptr, Xf, nullptr, Sc, nullptr, nullptr, nullptr,
        1024, 1024, 1024, 2048,
        2048LL * 1024, 2048LL * 1024, 2048LL * 2048);

    // D5: softmax rows -> f16 P
    softmax_f16<<<dim3(4 * 2048), blk, 0, stream>>>(Sc, P, 2048);

    // D6: out = P . Vt^T
    gemm_bt<f16, false, 0, 64><<<dim3(8, 16, 4), blk, 32768, stream>>>(
        P, nullptr, Vt, nullptr, out, nullptr, nullptr, nullptr,
        2048, 2048, 2048, 1024,
        2048LL * 2048, 1024LL * 2048, 2048LL * 1024);
}

// Round 8
// 293.586 us; speedup vs baseline: 1.1896x; 1.1896x over previous
//
#include <hip/hip_runtime.h>
#include <math.h>

// Round 8: all-f16 main GEMMs. M = WqWk^T is the only split-bf16 GEMM (tiny);
// T = Xf.Mf^T, V = Xf.Wvt_f, Sc = T.Xf^T, out = P.Vt^T all plain f16 MFMA.
// 6 dispatches (launch overhead ~10us each was ~30% of R6's wall time):
//   D1 prep_all : X->f16 || Wq,Wk bf16-split || Wv transpose->f16
//   D2 mt       : Mt = Wk_s Wq_s^T (split-bf16 3-MFMA) -> f16
//   D3 tv_gemm  : T = Xf.Mt^T (bx<8) || Vt = (Xf.Wv)^T (bx>=8), homogeneous f16
//   D4 scores   : Sc = T . Xf^T -> fp32
//   D5 softmax  : P = softmax(Sc) -> f16
//   D6 pv       : out = P . Vt^T -> fp32

typedef __bf16 bf16;
typedef _Float16 f16;
typedef __bf16 bf16x8 __attribute__((ext_vector_type(8)));
typedef __bf16 bf16x4 __attribute__((ext_vector_type(4)));
typedef _Float16 f16x4 __attribute__((ext_vector_type(4)));
typedef _Float16 f16x8 __attribute__((ext_vector_type(8)));
typedef float  f32x4  __attribute__((ext_vector_type(4)));

template<typename E> struct vec8_of;
template<> struct vec8_of<bf16> { using type = bf16x8; };
template<> struct vec8_of<f16>  { using type = f16x8; };

__device__ inline f32x4 mfma16(bf16x8 a, bf16x8 b, f32x4 c) {
    return __builtin_amdgcn_mfma_f32_16x16x32_bf16(a, b, c, 0, 0, 0);
}
__device__ inline f32x4 mfma16(f16x8 a, f16x8 b, f32x4 c) {
    return __builtin_amdgcn_mfma_f32_16x16x32_f16(a, b, c, 0, 0, 0);
}

#define AS1 __attribute__((address_space(1)))
#define AS3 __attribute__((address_space(3)))

template<typename E>
__device__ inline void async_load16(const E* g, void* l) {
    __builtin_amdgcn_global_load_lds((const AS1 unsigned int*)g,
                                     (AS3 unsigned int*)l, 16, 0, 0);
}

// C[M,N] = sum_k A[m,k]*B[n,k]  (B passed [N,K]-layout, leading dim ldb).
// SPLIT: hi/lo pairs, hh + hl + lh. BK: K-tile (32 split, 64 plain, swizzled).
// OUT_MODE: 0 fp32; 1 f16; 2 f16 transposed per-batch (V path).
template<typename E, bool SPLIT, int OUT_MODE, int BK>
__device__ __forceinline__ void gemm_body(
    char* __restrict__ smraw,
    const E* __restrict__ Ahi, const E* __restrict__ Alo,
    const E* __restrict__ Bhi, const E* __restrict__ Blo,
    float* __restrict__ Cf, f16* __restrict__ Ch,
    int K, int lda, int ldb, int ldc,
    long long sA, long long sB, long long sC,
    int bx, int by, int bz)
{
    using vec8 = typename vec8_of<E>::type;
    constexpr int TILE_BYTES = 128 * BK * (int)sizeof(E);   // 8192 or 16384
    constexpr int CPW = (TILE_BYTES / 1024) / 4;            // 1KB chunks per wave
    constexpr int SPR = (BK * (int)sizeof(E)) / 16;         // 16B slots per row
    constexpr int SWZ = (SPR == 8) ? 7 : 0;                 // swizzle mask (BK=64)

    Ahi += (long long)bz * sA;
    Bhi += (long long)bz * sB;
    if (SPLIT) { Alo += (long long)bz * sA; Blo += (long long)bz * sB; }

    const int tid  = threadIdx.x;
    const int lane = tid & 63;
    const int wave = tid >> 6;
    const int quad = lane >> 4;
    const int l16  = lane & 15;
    const int wm   = (wave >> 1) * 64;
    const int wn   = (wave & 1) * 64;

    const long long rowA0 = (long long)by * 128;
    const long long colB0 = (long long)bx * 128;

    int ofs[CPW], rr[CPW], cc8[CPW];
#pragma unroll
    for (int u = 0; u < CPW; u++) {
        ofs[u] = (wave * CPW + u) * 1024 + lane * 16;
        const int s = ofs[u] >> 4;
        rr[u]  = s / SPR;
        cc8[u] = (s & (SPR - 1)) ^ (rr[u] & SWZ);
    }

    f32x4 acc[4][4];
#pragma unroll
    for (int i = 0; i < 4; i++)
#pragma unroll
        for (int j = 0; j < 4; j++) acc[i][j] = (f32x4){0.f, 0.f, 0.f, 0.f};

    for (int k0 = 0; k0 < K; k0 += BK) {
#pragma unroll
        for (int u = 0; u < CPW; u++) {
            async_load16(Ahi + (rowA0 + rr[u]) * lda + k0 + cc8[u] * 8, smraw + 0 * TILE_BYTES + ofs[u]);
            async_load16(Bhi + (colB0 + rr[u]) * ldb + k0 + cc8[u] * 8, smraw + 1 * TILE_BYTES + ofs[u]);
            if (SPLIT) {
                async_load16(Alo + (rowA0 + rr[u]) * lda + k0 + cc8[u] * 8, smraw + 2 * TILE_BYTES + ofs[u]);
                async_load16(Blo + (colB0 + rr[u]) * ldb + k0 + cc8[u] * 8, smraw + 3 * TILE_BYTES + ofs[u]);
            }
        }
        __syncthreads();

#pragma unroll
        for (int kh = 0; kh < BK / 32; kh++) {
            const int kc8 = kh * 4 + quad;    // 16B chunk index within row
            vec8 a_hi[4], b_hi[4], a_lo[4], b_lo[4];
#pragma unroll
            for (int i = 0; i < 4; i++) {
                const int ra = wm + i * 16 + l16;
                const int rb = wn + i * 16 + l16;
                const int oa = ra * (SPR * 16) + ((kc8 ^ (ra & SWZ)) << 4);
                const int ob = rb * (SPR * 16) + ((kc8 ^ (rb & SWZ)) << 4);
                a_hi[i] = *(const vec8*)(smraw + 0 * TILE_BYTES + oa);
                b_hi[i] = *(const vec8*)(smraw + 1 * TILE_BYTES + ob);
                if (SPLIT) {
                    a_lo[i] = *(const vec8*)(smraw + 2 * TILE_BYTES + oa);
                    b_lo[i] = *(const vec8*)(smraw + 3 * TILE_BYTES + ob);
                }
            }
#pragma unroll
            for (int i = 0; i < 4; i++)
#pragma unroll
                for (int j = 0; j < 4; j++) {
                    acc[i][j] = mfma16(a_hi[i], b_hi[j], acc[i][j]);
                    if (SPLIT) {
                        acc[i][j] = mfma16(a_hi[i], b_lo[j], acc[i][j]);
                        acc[i][j] = mfma16(a_lo[i], b_hi[j], acc[i][j]);
                    }
                }
        }
        __syncthreads();
    }

    if (OUT_MODE == 2) {
        auto tr = (f16(*)[130])smraw;    // 128 x 130 f16 = 33280 B
#pragma unroll
        for (int i = 0; i < 4; i++)
#pragma unroll
            for (int j = 0; j < 4; j++)
#pragma unroll
                for (int e = 0; e < 4; e++)
                    tr[wn + j * 16 + l16][wm + i * 16 + quad * 4 + e] = (f16)acc[i][j][e];
        __syncthreads();
        const int batch = (int)(rowA0 >> 11);
        const int rib   = (int)(rowA0 & 2047);
        const int c  = tid >> 1;
        const int r0 = (tid & 1) << 6;
        f16* vt = Ch + (long long)batch * 1024 * 2048 + (long long)(colB0 + c) * ldc + rib + r0;
#pragma unroll
        for (int u = 0; u < 64; u += 8)
            *(f16x8*)(vt + u) = *(const f16x8*)&tr[c][r0 + u];
        return;
    }

    const long long cOff = (long long)bz * sC +
                           (rowA0 + wm + quad * 4) * (long long)ldc + colB0 + wn + l16;
#pragma unroll
    for (int i = 0; i < 4; i++)
#pragma unroll
        for (int e = 0; e < 4; e++) {
            const long long ro = cOff + (i * 16 + e) * ldc;
            if (OUT_MODE == 0) {
                float* rp = Cf + ro;
#pragma unroll
                for (int j = 0; j < 4; j++) rp[j * 16] = acc[i][j][e];
            } else {
                f16* rp = Ch + ro;
#pragma unroll
                for (int j = 0; j < 4; j++) rp[j * 16] = (f16)acc[i][j][e];
            }
        }
}

// ---- D1: blocks 0..8191 X->f16; 8192..10239 Wq/Wk bf16-split (natural);
//          10240..11263 Wv transpose -> f16.
__global__ __launch_bounds__(256) void prep_all(
    const float4* __restrict__ X, f16* __restrict__ Xf,
    const float* __restrict__ Wq, const float* __restrict__ Wk, const float* __restrict__ Wv,
    bf16* __restrict__ Wq_h, bf16* __restrict__ Wq_l,
    bf16* __restrict__ Wk_h, bf16* __restrict__ Wk_l,
    f16* __restrict__ Wvt_f)
{
    int b = blockIdx.x;
    if (b < 8192) {
        long long i = (long long)b * 256 + threadIdx.x;
        float4 v = X[i];
        f16x4 fv = {(f16)v.x, (f16)v.y, (f16)v.z, (f16)v.w};
        *(f16x4*)(Xf + 4 * i) = fv;
    } else if (b < 10240) {
        const int b2 = b - 8192;
        const float4* W = (const float4*)(b2 < 1024 ? Wq : Wk);
        bf16* hh = b2 < 1024 ? Wq_h : Wk_h;
        bf16* ll = b2 < 1024 ? Wq_l : Wk_l;
        long long i = (long long)(b2 & 1023) * 256 + threadIdx.x;
        float4 v = W[i];
        bf16 a0 = (bf16)v.x, a1 = (bf16)v.y, a2 = (bf16)v.z, a3 = (bf16)v.w;
        bf16x4 hv = {a0, a1, a2, a3};
        bf16x4 lv = {(bf16)(v.x - (float)a0), (bf16)(v.y - (float)a1),
                     (bf16)(v.z - (float)a2), (bf16)(v.w - (float)a3)};
        *(bf16x4*)(hh + 4 * i) = hv;
        *(bf16x4*)(ll + 4 * i) = lv;
    } else {
        const int b3 = b - 10240;
        __shared__ float t[32][33];
        const int bx = (b3 & 31) * 32, by = (b3 >> 5) * 32;
        const int tx = threadIdx.x & 31, ty = threadIdx.x >> 5;
#pragma unroll
        for (int i = 0; i < 32; i += 8)
            t[ty + i][tx] = Wv[(long long)(by + ty + i) * 1024 + bx + tx];
        __syncthreads();
#pragma unroll
        for (int i = 0; i < 32; i += 8) {
            long long o = (long long)(bx + ty + i) * 1024 + by + tx;
            Wvt_f[o] = (f16)t[tx][ty + i];
        }
    }
}

// ---- D3: T = Xf.Mt^T (bx<8) || Vt = (Xf.Wv)^T (bx>=8). Homogeneous f16 BK=64.
__global__ __launch_bounds__(256) void tv_gemm(
    const f16* __restrict__ Xf, const f16* __restrict__ Mt_f,
    const f16* __restrict__ Wvt_f,
    f16* __restrict__ T, f16* __restrict__ Vt)
{
    extern __shared__ char smraw[];
    if (blockIdx.x < 8)
        gemm_body<f16, false, 1, 64>(smraw, Xf, nullptr, Mt_f, nullptr,
                                     nullptr, T, 1024, 1024, 1024, 1024,
                                     0, 0, 0, blockIdx.x, blockIdx.y, 0);
    else
        gemm_body<f16, false, 2, 64>(smraw, Xf, nullptr, Wvt_f, nullptr,
                                     nullptr, Vt, 1024, 1024, 1024, 2048,
                                     0, 0, 0, blockIdx.x - 8, blockIdx.y, 0);
}

// ---- generic GEMM wrapper (D2, D4, D6)
template<typename E, bool SPLIT, int OUT_MODE, int BK>
__global__ __launch_bounds__(256) void gemm_bt(
    const E* __restrict__ Ahi, const E* __restrict__ Alo,
    const E* __restrict__ Bhi, const E* __restrict__ Blo,
    float* __restrict__ Cf, f16* __restrict__ Ch,
    int K, int lda, int ldb, int ldc,
    long long sA, long long sB, long long sC)
{
    extern __shared__ char smraw[];
    gemm_body<E, SPLIT, OUT_MODE, BK>(smraw, Ahi, Alo, Bhi, Blo, Cf, Ch,
                                      K, lda, ldb, ldc, sA, sB, sC,
                                      blockIdx.x, blockIdx.y, blockIdx.z);
}

// ---- D5: row softmax fp32 -> f16.
__global__ __launch_bounds__(256) void softmax_f16(const float* __restrict__ S,
                                                   f16* __restrict__ P, int n)
{
    const long long row = blockIdx.x;
    const float* p = S + row * (long long)n;
    f16* q = P + row * (long long)n;
    const int tid = threadIdx.x;
    const int wv = tid >> 6, lane = tid & 63;

    float v[8];
    float m = -3.4e38f;
#pragma unroll
    for (int i = 0; i < 8; i++) { v[i] = p[tid + (i << 8)]; m = fmaxf(m, v[i]); }
#pragma unroll
    for (int off = 32; off > 0; off >>= 1) m = fmaxf(m, __shfl_xor(m, off, 64));

    __shared__ float red[4];
    if (lane == 0) red[wv] = m;
    __syncthreads();
    m = fmaxf(fmaxf(red[0], red[1]), fmaxf(red[2], red[3]));

    float s = 0.f;
#pragma unroll
    for (int i = 0; i < 8; i++) { v[i] = __expf(v[i] - m); s += v[i]; }
#pragma unroll
    for (int off = 32; off > 0; off >>= 1) s += __shfl_xor(s, off, 64);
    __syncthreads();
    if (lane == 0) red[wv] = s;
    __syncthreads();
    s = red[0] + red[1] + red[2] + red[3];

    const float inv = 1.0f / s;
#pragma unroll
    for (int i = 0; i < 8; i++) q[tid + (i << 8)] = (f16)(v[i] * inv);
}

extern "C" void kernel_launch(void* const* d_in, const int* in_sizes, int n_in,
                              void* d_out, int out_size, void* d_ws, size_t ws_size,
                              hipStream_t stream) {
    const float* X  = (const float*)d_in[0];   // [8192,1024]
    const float* Wq = (const float*)d_in[1];   // [1024,1024]
    const float* Wk = (const float*)d_in[2];
    const float* Wv = (const float*)d_in[3];
    float* out = (float*)d_out;                // [8192,1024]

    char* w = (char*)d_ws;
    const long long MB = 1024LL * 1024;
    f16*  Xf    = (f16*) (w + 0 * MB);     // 16 MB
    bf16* Wq_h  = (bf16*)(w + 16 * MB);    // 2 MB
    bf16* Wq_l  = (bf16*)(w + 18 * MB);
    bf16* Wk_h  = (bf16*)(w + 20 * MB);
    bf16* Wk_l  = (bf16*)(w + 22 * MB);
    f16*  Wvt_f = (f16*) (w + 24 * MB);    // 2 MB (transposed)
    f16*  Mt_f  = (f16*) (w + 26 * MB);    // 2 MB
    f16*  T     = (f16*) (w + 28 * MB);    // 16 MB [8192,1024]
    f16*  Vt    = (f16*) (w + 44 * MB);    // 16 MB [4][1024][2048]
    float* Sc   = (float*)(w + 60 * MB);   // 64 MB
    f16*  P     = (f16*) (w + 124 * MB);   // 32 MB -> ends 156 MB

    dim3 blk(256);

    // D1: X->f16 || Wq,Wk split || Wv transpose->f16
    prep_all<<<dim3(11264), blk, 0, stream>>>(
        (const float4*)X, Xf, Wq, Wk, Wv, Wq_h, Wq_l, Wk_h, Wk_l, Wvt_f);

    // D2: Mt = Wk_s Wq_s^T (split bf16, 3-MFMA) -> f16 (same orientation as R6)
    gemm_bt<bf16, true, 1, 32><<<dim3(8, 8, 1), blk, 32768, stream>>>(
        Wk_h, Wk_l, Wq_h, Wq_l, nullptr, Mt_f,
        1024, 1024, 1024, 1024, 0, 0, 0);

    // D3: T || Vt (homogeneous f16 BK=64; 33280 B LDS for the V transpose)
    tv_gemm<<<dim3(16, 64, 1), blk, 33280, stream>>>(Xf, Mt_f, Wvt_f, T, Vt);

    // D4: Sc = T . Xf^T per batch -> fp32
    gemm_bt<f16, false, 0, 64><<<dim3(16, 16, 4), blk, 32768, stream>>>(
        T, nullptr, Xf, nullptr, Sc, nullptr,
        1024, 1024, 1024, 2048,
        2048LL * 1024, 2048LL * 1024, 2048LL * 2048);

    // D5: softmax rows -> f16 P
    softmax_f16<<<dim3(4 * 2048), blk, 0, stream>>>(Sc, P, 2048);

    // D6: out = P . Vt^T
    gemm_bt<f16, false, 0, 64><<<dim3(8, 16, 4), blk, 32768, stream>>>(
        P, nullptr, Vt, nullptr, out, nullptr,
        2048, 2048, 2048, 1024,
        2048LL * 2048, 1024LL * 2048, 2048LL * 1024);
}